// Round 8
// baseline (469.527 us; speedup 1.0000x reference)
//
#include <hip/hip_runtime.h>

// out = A @ x, COO (rows sorted), E=800000, N=50000, D=128.
// Pipeline (2 launches, no out-atomics, no memset):
//  prep_kernel: (a) x fp32 -> bf16 into ws; (b) CSR row_ptr from sorted
//               rows[]; zero-fill empty out rows; zero the work counter.
//  agg_kernel:  persistent waves dynamically grab chunks of RPC rows.
//               Chunk edges are contiguous; lane l owns dims {2l,2l+1}
//               (one uint = 2 bf16), fp32 register accumulate. Row flush is
//               a UNIFORM scalar compare (edge idx == row_ptr[r+1]) -> plain
//               NT store; rows[] never read here, no per-edge readlane(rj).
// Fallback (ws too small): R3-proven fp32 atomic path + memset.

#define D_FEAT 128
#define TOTAL_WAVES 8192
#define WAVES_PER_BLOCK 4
#define BLOCK_THREADS 256
#define NBLOCKS (TOTAL_WAVES / WAVES_PER_BLOCK)
#define PF 8
#define RPC 2  // rows per dynamically-grabbed chunk (~32 edges)

typedef float v2f __attribute__((ext_vector_type(2)));

__device__ __forceinline__ float bcast_f(float v, int j) {
    return __int_as_float(__builtin_amdgcn_readlane(__float_as_int(v), j));
}

__device__ __forceinline__ unsigned short f2bf_rne(float f) {
    unsigned int b = __float_as_uint(f);
    b += 0x7fffu + ((b >> 16) & 1u);
    return (unsigned short)(b >> 16);
}

__global__ __launch_bounds__(256) void prep_kernel(
    const float* __restrict__ x, const int* __restrict__ rows,
    unsigned short* __restrict__ xb, int* __restrict__ row_ptr,
    int* __restrict__ ctr, float* __restrict__ out, int n4, int n_edges,
    int n_nodes) {
    const int tid = blockIdx.x * blockDim.x + threadIdx.x;
    const int nth = gridDim.x * blockDim.x;
    if (tid == 0) *ctr = 0;
    // (a) fp32 -> bf16 (RNE), float4 -> ushort4
    const float4* __restrict__ x4 = (const float4*)x;
    ushort4* __restrict__ o4 = (ushort4*)xb;
    for (int i = tid; i < n4; i += nth) {
        float4 f = x4[i];
        ushort4 o;
        o.x = f2bf_rne(f.x);
        o.y = f2bf_rne(f.y);
        o.z = f2bf_rne(f.z);
        o.w = f2bf_rne(f.w);
        o4[i] = o;
    }
    // (b) row_ptr[r] = first edge with rows[e] >= r, r in [0, n_nodes];
    //     zero-fill out rows that have no edges (expected ~0 such rows).
    for (int e = tid; e <= n_edges; e += nth) {
        int r, rp;
        if (e < n_edges) {
            r  = rows[e];
            rp = (e == 0) ? -1 : rows[e - 1];
        } else {
            r  = n_nodes;
            rp = rows[n_edges - 1];
        }
        for (int q = rp + 1; q <= r; ++q)
            if (q <= n_nodes) row_ptr[q] = e;
        for (int q = rp + 1; q < r && q < n_nodes; ++q) {  // empty rows
            float4* zo = (float4*)(out + (size_t)q * D_FEAT);
            for (int k = 0; k < D_FEAT / 4; ++k)
                zo[k] = make_float4(0.f, 0.f, 0.f, 0.f);
        }
    }
}

__global__ __launch_bounds__(BLOCK_THREADS) void agg_bf16_kernel(
    const unsigned int* __restrict__ xb,  // [N][64] uints, 2 bf16 each
    const float* __restrict__ vals, const int* __restrict__ cols,
    const int* __restrict__ row_ptr, int* __restrict__ ctr,
    float* __restrict__ out, int n_nodes) {
    const int lane = threadIdx.x & 63;
    for (;;) {
        int c = 0;
        if (lane == 0) c = atomicAdd(ctr, 1);
        c = __shfl(c, 0);
        const int r0 = c * RPC;
        if (r0 >= n_nodes) return;
        const int r1 = min(r0 + RPC, n_nodes);
        const int e_beg = row_ptr[r0];
        const int e_end = row_ptr[r1];
        if (e_beg >= e_end) continue;  // all rows empty (prep zero-filled)

        int r = r0;
        int next_b = row_ptr[r0 + 1];  // uniform scalar row boundary
        int idx = e_beg;               // uniform scalar edge index
        float2 acc = make_float2(0.f, 0.f);

        for (int e0 = e_beg; e0 < e_end; e0 += 64) {
            const int nb = min(e_end - e0, 64);
            int myc = 0;
            float myv = 0.f;
            if (lane < nb) {  // streamed metadata: keep L2 for x
                myc = __builtin_nontemporal_load(cols + e0 + lane);
                myv = __builtin_nontemporal_load(vals + e0 + lane);
            }
            for (int j0 = 0; j0 < nb; j0 += PF) {
                const int m = min(nb - j0, PF);
                unsigned int xu[PF];
                float vj[PF];
#pragma unroll
                for (int t = 0; t < PF; ++t) {
                    if (t < m) {
                        const int cj = __builtin_amdgcn_readlane(myc, j0 + t);
                        vj[t] = bcast_f(myv, j0 + t);
                        xu[t] = xb[(size_t)cj * (D_FEAT / 2) + lane];
                    }
                }
#pragma unroll
                for (int t = 0; t < PF; ++t) {
                    if (t < m) {
                        while (idx == next_b) {  // uniform: row r finished
                            v2f st; st.x = acc.x; st.y = acc.y;
                            __builtin_nontemporal_store(
                                st, (v2f*)(out + (size_t)r * D_FEAT + 2 * lane));
                            acc.x = 0.f; acc.y = 0.f;
                            ++r;
                            next_b = row_ptr[r + 1];
                        }
                        const float x0 = __uint_as_float(xu[t] << 16);
                        const float x1 = __uint_as_float(xu[t] & 0xffff0000u);
                        acc.x = fmaf(vj[t], x0, acc.x);
                        acc.y = fmaf(vj[t], x1, acc.y);
                        ++idx;
                    }
                }
            }
        }
        v2f st; st.x = acc.x; st.y = acc.y;
        __builtin_nontemporal_store(
            st, (v2f*)(out + (size_t)r * D_FEAT + 2 * lane));
        // rows in (r, r1) have no edges -> zero-filled by prep
    }
}

// Fallback (R3-proven fp32 atomic path) if ws is too small.
__global__ __launch_bounds__(BLOCK_THREADS) void agg_f32_kernel(
    const float* __restrict__ x, const float* __restrict__ vals,
    const int* __restrict__ rows, const int* __restrict__ cols,
    float* __restrict__ out, int n_edges, int epw) {
    const int wave = blockIdx.x * WAVES_PER_BLOCK + (threadIdx.x >> 6);
    const int lane = threadIdx.x & 63;

    const int start = wave * epw;
    if (start >= n_edges) return;
    int end = start + epw;
    if (end > n_edges) end = n_edges;

    const float2* __restrict__ x2 = (const float2*)x;
    const int first_row = rows[start];
    const int last_row  = rows[end - 1];

    float2 acc = make_float2(0.f, 0.f);
    int cur_row = first_row;

    for (int e0 = start; e0 < end; e0 += 64) {
        const int nb = min(end - e0, 64);
        int myc = 0, myr = 0;
        float myv = 0.f;
        if (lane < nb) {
            myc = cols[e0 + lane];
            myr = rows[e0 + lane];
            myv = vals[e0 + lane];
        }
        for (int j0 = 0; j0 < nb; j0 += PF) {
            const int m = min(nb - j0, PF);
            float2 xv[PF];
            int    rj[PF];
            float  vj[PF];
#pragma unroll
            for (int t = 0; t < PF; ++t) {
                if (t < m) {
                    const int cj = __builtin_amdgcn_readlane(myc, j0 + t);
                    rj[t] = __builtin_amdgcn_readlane(myr, j0 + t);
                    vj[t] = bcast_f(myv, j0 + t);
                    xv[t] = x2[(size_t)cj * (D_FEAT / 2) + lane];
                }
            }
#pragma unroll
            for (int t = 0; t < PF; ++t) {
                if (t < m) {
                    if (rj[t] != cur_row) {
                        float* o = out + (size_t)cur_row * D_FEAT + 2 * lane;
                        if (cur_row == first_row || cur_row == last_row) {
                            atomicAdd(o,     acc.x);
                            atomicAdd(o + 1, acc.y);
                        } else {
                            v2f st; st.x = acc.x; st.y = acc.y;
                            __builtin_nontemporal_store(st, (v2f*)o);
                        }
                        acc.x = 0.f; acc.y = 0.f;
                        cur_row = rj[t];
                    }
                    acc.x = fmaf(vj[t], xv[t].x, acc.x);
                    acc.y = fmaf(vj[t], xv[t].y, acc.y);
                }
            }
        }
    }
    float* o = out + (size_t)cur_row * D_FEAT + 2 * lane;
    atomicAdd(o,     acc.x);
    atomicAdd(o + 1, acc.y);
}

extern "C" void kernel_launch(void* const* d_in, const int* in_sizes, int n_in,
                              void* d_out, int out_size, void* d_ws, size_t ws_size,
                              hipStream_t stream) {
    const float* x    = (const float*)d_in[0];
    const float* vals = (const float*)d_in[1];
    const int*   rows = (const int*)d_in[2];
    const int*   cols = (const int*)d_in[3];
    float*       out  = (float*)d_out;

    const int n_edges = in_sizes[1];
    const int n_x     = in_sizes[0];          // N*D floats
    const int n_nodes = out_size / D_FEAT;    // N

    const size_t xb_bytes = (size_t)n_x * sizeof(unsigned short);
    const size_t rp_off   = (xb_bytes + 255) & ~(size_t)255;
    const size_t ctr_off  = rp_off + (size_t)(n_nodes + 1) * sizeof(int);
    const size_t need     = ctr_off + sizeof(int);

    if (ws_size >= need) {
        unsigned short* xb = (unsigned short*)d_ws;
        int* row_ptr = (int*)((char*)d_ws + rp_off);
        int* ctr     = (int*)((char*)d_ws + ctr_off);
        prep_kernel<<<2048, 256, 0, stream>>>(x, rows, xb, row_ptr, ctr, out,
                                              n_x / 4, n_edges, n_nodes);
        agg_bf16_kernel<<<NBLOCKS, BLOCK_THREADS, 0, stream>>>(
            (const unsigned int*)xb, vals, cols, row_ptr, ctr, out, n_nodes);
    } else {
        (void)hipMemsetAsync(d_out, 0, (size_t)out_size * sizeof(float), stream);
        const int epw    = (n_edges + TOTAL_WAVES - 1) / TOTAL_WAVES;
        agg_f32_kernel<<<NBLOCKS, BLOCK_THREADS, 0, stream>>>(
            x, vals, rows, cols, out, n_edges, epw);
    }
}

// Round 9
// 119.306 us; speedup vs baseline: 3.9355x; 3.9355x over previous
//
#include <hip/hip_runtime.h>

// out = A @ x, COO (rows sorted), E=800000, N=50000, D=128.
// R6-proven STATIC edge-balanced split (no work-queue atomics — R8 showed
// same-address cross-XCD atomics cost ~12 ns each) + compressed metadata:
//  prep: x fp32 -> bf16 (xb); pack (col<<16)|bf16(val) into one uint (cv).
//  agg:  wave owns exactly 128 edges (E%128==0 -> perfect balance, 64-aligned
//        groups). Per 64-edge group: one ballot(row!=next_row) gives a flush
//        bitmask (per-edge test = free SALU bit-test); one readlane per edge
//        broadcasts packed (col,val); gather 2 bf16 dims/lane; fp32 acc.
//        Interior rows: sole writer -> NT store. First/final rows of the
//        wave range: atomicAdd onto memset-zeroed out.
// Fallback (ws small / shape unexpected): R3-proven fp32 atomic path.

#define D_FEAT 128
#define EPW 128           // edges per wave (multiple of 64)
#define WAVES_PER_BLOCK 4
#define BLOCK_THREADS 256
#define PF 8

typedef float v2f __attribute__((ext_vector_type(2)));

__device__ __forceinline__ float bcast_f(float v, int j) {
    return __int_as_float(__builtin_amdgcn_readlane(__float_as_int(v), j));
}

__device__ __forceinline__ unsigned short f2bf_rne(float f) {
    unsigned int b = __float_as_uint(f);
    b += 0x7fffu + ((b >> 16) & 1u);
    return (unsigned short)(b >> 16);
}

__global__ __launch_bounds__(256) void prep_kernel(
    const float* __restrict__ x, const float* __restrict__ vals,
    const int* __restrict__ cols, unsigned short* __restrict__ xb,
    unsigned int* __restrict__ cv, int n4, int n_edges) {
    const int tid = blockIdx.x * blockDim.x + threadIdx.x;
    const int nth = gridDim.x * blockDim.x;
    // (a) x fp32 -> bf16 (RNE), float4 -> ushort4
    const float4* __restrict__ x4 = (const float4*)x;
    ushort4* __restrict__ o4 = (ushort4*)xb;
    for (int i = tid; i < n4; i += nth) {
        float4 f = x4[i];
        ushort4 o;
        o.x = f2bf_rne(f.x);
        o.y = f2bf_rne(f.y);
        o.z = f2bf_rne(f.z);
        o.w = f2bf_rne(f.w);
        o4[i] = o;
    }
    // (b) pack (col<<16) | bf16(val)
    for (int e = tid; e < n_edges; e += nth) {
        cv[e] = ((unsigned int)cols[e] << 16) | (unsigned int)f2bf_rne(vals[e]);
    }
}

__global__ __launch_bounds__(BLOCK_THREADS) void agg_bf16_kernel(
    const unsigned int* __restrict__ xb,  // [N][64] uints, 2 bf16 each
    const unsigned int* __restrict__ cv,  // [E] packed (col<<16)|bf16(val)
    const int* __restrict__ rows, float* __restrict__ out, int n_edges) {
    const int wave = blockIdx.x * WAVES_PER_BLOCK + (threadIdx.x >> 6);
    const int lane = threadIdx.x & 63;

    const int start = wave * EPW;
    if (start >= n_edges) return;
    const int end = min(start + EPW, n_edges);  // multiple of 64 by host guard

    const int first_row = rows[start];  // wave-uniform broadcast load
    float2 acc = make_float2(0.f, 0.f);
    int cur_row = first_row;

    for (int e0 = start; e0 < end; e0 += 64) {
        const unsigned int mycv = __builtin_nontemporal_load(cv + e0 + lane);
        const int myr = __builtin_nontemporal_load(rows + e0 + lane);
        const int nxt = __shfl(myr, (lane + 1) & 63);
        const unsigned long long bmask =
            __ballot(myr != nxt) & 0x7fffffffffffffffULL;  // bit63 handled at
                                                           // next group start
        const int g0 = __builtin_amdgcn_readfirstlane(myr);
        if (g0 != cur_row) {  // cur_row's last edge was previous group's #63
            float* o = out + (size_t)cur_row * D_FEAT + 2 * lane;
            if (cur_row == first_row) {
                atomicAdd(o, acc.x);
                atomicAdd(o + 1, acc.y);
            } else {
                v2f st; st.x = acc.x; st.y = acc.y;
                __builtin_nontemporal_store(st, (v2f*)o);
            }
            acc.x = 0.f; acc.y = 0.f;
            cur_row = g0;
        }
#pragma unroll
        for (int j0 = 0; j0 < 64; j0 += PF) {
            unsigned int sv[PF];
            unsigned int xu[PF];
#pragma unroll
            for (int t = 0; t < PF; ++t) {  // issue PF independent gathers
                sv[t] = (unsigned int)__builtin_amdgcn_readlane((int)mycv, j0 + t);
                xu[t] = xb[(size_t)(sv[t] >> 16) * (D_FEAT / 2) + lane];
            }
#pragma unroll
            for (int t = 0; t < PF; ++t) {
                const float vf = __uint_as_float(sv[t] << 16);  // bf16 val
                acc.x = fmaf(vf, __uint_as_float(xu[t] << 16), acc.x);
                acc.y = fmaf(vf, __uint_as_float(xu[t] & 0xffff0000u), acc.y);
                if ((bmask >> (j0 + t)) & 1ULL) {  // row ends at this edge
                    const int fr = __builtin_amdgcn_readlane(myr, j0 + t);
                    float* o = out + (size_t)fr * D_FEAT + 2 * lane;
                    if (fr == first_row) {
                        atomicAdd(o, acc.x);
                        atomicAdd(o + 1, acc.y);
                    } else {
                        v2f st; st.x = acc.x; st.y = acc.y;
                        __builtin_nontemporal_store(st, (v2f*)o);
                    }
                    acc.x = 0.f; acc.y = 0.f;
                }
            }
        }
        cur_row = __builtin_amdgcn_readlane(myr, 63);
    }
    // Final row of the range: possibly shared with the next wave -> atomic.
    float* o = out + (size_t)cur_row * D_FEAT + 2 * lane;
    atomicAdd(o, acc.x);
    atomicAdd(o + 1, acc.y);
}

// Fallback (R3-proven fp32 atomic path) for unexpected shapes / small ws.
__global__ __launch_bounds__(BLOCK_THREADS) void agg_f32_kernel(
    const float* __restrict__ x, const float* __restrict__ vals,
    const int* __restrict__ rows, const int* __restrict__ cols,
    float* __restrict__ out, int n_edges, int epw) {
    const int wave = blockIdx.x * WAVES_PER_BLOCK + (threadIdx.x >> 6);
    const int lane = threadIdx.x & 63;

    const int start = wave * epw;
    if (start >= n_edges) return;
    int end = start + epw;
    if (end > n_edges) end = n_edges;

    const float2* __restrict__ x2 = (const float2*)x;
    const int first_row = rows[start];
    const int last_row  = rows[end - 1];

    float2 acc = make_float2(0.f, 0.f);
    int cur_row = first_row;

    for (int e0 = start; e0 < end; e0 += 64) {
        const int nb = min(end - e0, 64);
        int myc = 0, myr = 0;
        float myv = 0.f;
        if (lane < nb) {
            myc = cols[e0 + lane];
            myr = rows[e0 + lane];
            myv = vals[e0 + lane];
        }
        for (int j0 = 0; j0 < nb; j0 += PF) {
            const int m = min(nb - j0, PF);
            float2 xv[PF];
            int    rj[PF];
            float  vj[PF];
#pragma unroll
            for (int t = 0; t < PF; ++t) {
                if (t < m) {
                    const int cj = __builtin_amdgcn_readlane(myc, j0 + t);
                    rj[t] = __builtin_amdgcn_readlane(myr, j0 + t);
                    vj[t] = bcast_f(myv, j0 + t);
                    xv[t] = x2[(size_t)cj * (D_FEAT / 2) + lane];
                }
            }
#pragma unroll
            for (int t = 0; t < PF; ++t) {
                if (t < m) {
                    if (rj[t] != cur_row) {
                        float* o = out + (size_t)cur_row * D_FEAT + 2 * lane;
                        if (cur_row == first_row || cur_row == last_row) {
                            atomicAdd(o,     acc.x);
                            atomicAdd(o + 1, acc.y);
                        } else {
                            v2f st; st.x = acc.x; st.y = acc.y;
                            __builtin_nontemporal_store(st, (v2f*)o);
                        }
                        acc.x = 0.f; acc.y = 0.f;
                        cur_row = rj[t];
                    }
                    acc.x = fmaf(vj[t], xv[t].x, acc.x);
                    acc.y = fmaf(vj[t], xv[t].y, acc.y);
                }
            }
        }
    }
    float* o = out + (size_t)cur_row * D_FEAT + 2 * lane;
    atomicAdd(o,     acc.x);
    atomicAdd(o + 1, acc.y);
}

extern "C" void kernel_launch(void* const* d_in, const int* in_sizes, int n_in,
                              void* d_out, int out_size, void* d_ws, size_t ws_size,
                              hipStream_t stream) {
    const float* x    = (const float*)d_in[0];
    const float* vals = (const float*)d_in[1];
    const int*   rows = (const int*)d_in[2];
    const int*   cols = (const int*)d_in[3];
    float*       out  = (float*)d_out;

    const int n_edges = in_sizes[1];
    const int n_x     = in_sizes[0];          // N*D floats
    const int n_nodes = out_size / D_FEAT;    // N

    (void)hipMemsetAsync(d_out, 0, (size_t)out_size * sizeof(float), stream);

    const size_t xb_bytes = (size_t)n_x * sizeof(unsigned short);
    const size_t cv_off   = (xb_bytes + 255) & ~(size_t)255;
    const size_t need     = cv_off + (size_t)n_edges * sizeof(unsigned int);

    const bool fast_ok = (ws_size >= need) && (n_edges % 64 == 0) &&
                         (n_nodes <= 65536) && (n_x % 4 == 0);

    if (fast_ok) {
        unsigned short* xb = (unsigned short*)d_ws;
        unsigned int*   cv = (unsigned int*)((char*)d_ws + cv_off);
        prep_kernel<<<2048, 256, 0, stream>>>(x, vals, cols, xb, cv,
                                              n_x / 4, n_edges);
        const int waves  = (n_edges + EPW - 1) / EPW;
        const int blocks = (waves + WAVES_PER_BLOCK - 1) / WAVES_PER_BLOCK;
        agg_bf16_kernel<<<blocks, BLOCK_THREADS, 0, stream>>>(
            (const unsigned int*)xb, cv, rows, out, n_edges);
    } else {
        const int total_waves = 8192;
        const int epw    = (n_edges + total_waves - 1) / total_waves;
        const int blocks = total_waves / WAVES_PER_BLOCK;
        agg_f32_kernel<<<blocks, BLOCK_THREADS, 0, stream>>>(
            x, vals, rows, cols, out, n_edges, epw);
    }
}